// Round 1
// baseline (2218.731 us; speedup 1.0000x reference)
//
#include <hip/hip_runtime.h>
#include <hip/hip_bf16.h>

// Problem: LIF neuron layer.
//   lif_input[T, NOUT] = x[T, NIN] @ W[NOUT, NIN]^T   (fp32 GEMM, K-major both sides)
//   then sequential Euler scan over t = 1..T-1 producing spikes[T, NOUT].
// T=2000, NIN=8192, NOUT=4096, dt=0.001.

#define BM 64
#define BN 64
#define BK 16
#define PAD 4  // LDS leading-dim pad: keeps 16B alignment for potential b128 reads

__global__ __launch_bounds__(256) void gemm_bt(const float* __restrict__ A, // [M,K]
                                               const float* __restrict__ B, // [N,K]
                                               float* __restrict__ C,       // [M,N]
                                               int M, int N, int K) {
    __shared__ float As[BK][BM + PAD];
    __shared__ float Bs[BK][BN + PAD];

    const int bm = blockIdx.y * BM;
    const int bn = blockIdx.x * BN;
    const int tid = threadIdx.x;        // 0..255
    const int tx = tid & 15;            // 0..15 -> n micro
    const int ty = tid >> 4;            // 0..15 -> m micro

    // Staging mapping: each thread loads one float4 along K.
    const int lrow = tid >> 2;          // 0..63 (tile row)
    const int lk   = (tid & 3) * 4;     // 0,4,8,12 (k offset)

    float acc[4][4];
#pragma unroll
    for (int i = 0; i < 4; ++i)
#pragma unroll
        for (int j = 0; j < 4; ++j) acc[i][j] = 0.0f;

    for (int k0 = 0; k0 < K; k0 += BK) {
        // A tile (guard rows past M with zeros)
        const int am = bm + lrow;
        float4 av;
        if (am < M) av = *(const float4*)(A + (size_t)am * K + k0 + lk);
        else        av = make_float4(0.f, 0.f, 0.f, 0.f);
        As[lk + 0][lrow] = av.x;
        As[lk + 1][lrow] = av.y;
        As[lk + 2][lrow] = av.z;
        As[lk + 3][lrow] = av.w;

        // B tile (N=4096 divisible by BN, no guard)
        const int bnr = bn + lrow;
        float4 bv = *(const float4*)(B + (size_t)bnr * K + k0 + lk);
        Bs[lk + 0][lrow] = bv.x;
        Bs[lk + 1][lrow] = bv.y;
        Bs[lk + 2][lrow] = bv.z;
        Bs[lk + 3][lrow] = bv.w;

        __syncthreads();

#pragma unroll
        for (int k = 0; k < BK; ++k) {
            float a[4], b[4];
#pragma unroll
            for (int i = 0; i < 4; ++i) a[i] = As[k][ty * 4 + i];
#pragma unroll
            for (int j = 0; j < 4; ++j) b[j] = Bs[k][tx * 4 + j];
#pragma unroll
            for (int i = 0; i < 4; ++i)
#pragma unroll
                for (int j = 0; j < 4; ++j) acc[i][j] += a[i] * b[j];
        }
        __syncthreads();
    }

#pragma unroll
    for (int i = 0; i < 4; ++i) {
        const int m = bm + ty * 4 + i;
        if (m < M) {
            float* cp = C + (size_t)m * N + bn + tx * 4;
#pragma unroll
            for (int j = 0; j < 4; ++j) cp[j] = acc[i][j];
        }
    }
}

// Sequential LIF scan: one thread per neuron. Reference semantics:
//   v = v - (dt*tau)*(v - v_rest)          [separate mul + sub, NOT fma]
//   v += inp  if refrac == 0               [gate on PRE-decrement refrac]
//   refrac = refrac > 0 ? refrac - dt : 0
//   spike = (v - v_th >= 0)
//   if spike: refrac = t_ref, v = v_reset
// out row 0 is zeros; step t consumes inp[t] for t = 1..T-1.
__global__ __launch_bounds__(64) void lif_scan(const float* __restrict__ inp, // [T, N]
                                               const float* __restrict__ v_th_p,
                                               const float* __restrict__ v_rest_p,
                                               const float* __restrict__ v_reset_p,
                                               const float* __restrict__ t_ref_p,
                                               const float* __restrict__ tau_p,
                                               float* __restrict__ out,       // [T, N]
                                               int T, int N) {
    const int j = blockIdx.x * 64 + threadIdx.x;
    if (j >= N) return;

    const float vth   = v_th_p[j];
    const float vrest = v_rest_p[j];
    const float vres  = v_reset_p[j];
    const float tref  = t_ref_p[j];
    const float c     = __fmul_rn(0.001f, tau_p[j]);   // dt * tau in fp32

    float v = vrest;
    float refrac = 0.0f;

    out[j] = 0.0f;  // row 0 stays zero

#pragma unroll 8
    for (int t = 1; t < T; ++t) {
        const float in = inp[(size_t)t * N + j];
        // leak: separate mul + sub to match non-fused reference rounding
        const float d = __fmul_rn(c, __fsub_rn(v, vrest));
        v = __fsub_rn(v, d);
        // integrate if not refractory (pre-decrement gate)
        v = (refrac == 0.0f) ? __fadd_rn(v, in) : v;
        // countdown
        refrac = (refrac > 0.0f) ? (refrac - 0.001f) : 0.0f;
        // spike
        const bool s = (__fsub_rn(v, vth) >= 0.0f);
        out[(size_t)t * N + j] = s ? 1.0f : 0.0f;
        refrac = s ? tref : refrac;
        v      = s ? vres : v;
    }
}

extern "C" void kernel_launch(void* const* d_in, const int* in_sizes, int n_in,
                              void* d_out, int out_size, void* d_ws, size_t ws_size,
                              hipStream_t stream) {
    const float* x       = (const float*)d_in[0];  // [T, NIN]
    const float* w       = (const float*)d_in[1];  // [NOUT, NIN]
    const float* v_th    = (const float*)d_in[2];
    const float* v_rest  = (const float*)d_in[3];
    const float* v_reset = (const float*)d_in[4];
    const float* t_ref   = (const float*)d_in[5];
    const float* tau     = (const float*)d_in[6];
    float* out = (float*)d_out;

    const int T = 2000, NIN = 8192, NOUT = 4096;
    float* lif = (float*)d_ws;  // [T, NOUT] fp32 = 32 MB scratch

    dim3 ggrid(NOUT / BN, (T + BM - 1) / BM);
    gemm_bt<<<ggrid, 256, 0, stream>>>(x, w, lif, T, NOUT, NIN);

    lif_scan<<<NOUT / 64, 64, 0, stream>>>(lif, v_th, v_rest, v_reset, t_ref, tau,
                                           out, T, NOUT);
}

// Round 3
// 1187.864 us; speedup vs baseline: 1.8678x; 1.8678x over previous
//
#include <hip/hip_runtime.h>
#include <hip/hip_bf16.h>

// LIF layer: lif_input[T,NOUT] = x[T,NIN] @ W[NOUT,NIN]^T (fp32), then sequential scan.
// fp32 GEMM emulated on the matrix pipe via fp16 2-way SCALED split, 3 MFMA products:
//   a = a0 + a1*2^-12  (a1 stored pre-scaled by 2^12 to dodge fp16 subnormal flush;
//                       w's lo parts are ALL subnormal unscaled: |w|<=0.1 -> lo<=2.4e-5)
//   C = acc0(A0B0) + 2^-12 * acc1(A0B1 + A1B0)
// Residual ~3*2^-24|ab| per term -> lif_input error ~1e-6, below fp32-reorder noise
// (which passed round 1 at absmax 0.0). Dual accumulators keep scales separate.

#define T_STEPS 2000
#define NIN_K   8192
#define NOUT_N  4096
#define MPAD    2048

typedef __attribute__((ext_vector_type(8))) _Float16 half8;  // 8 fp16 = 4 VGPRs
typedef __attribute__((ext_vector_type(4))) float f32x4;

// async global->LDS, 16B per lane, LDS dest = wave-uniform base + lane*16
#define GLL16(g, l)                                                              \
    __builtin_amdgcn_global_load_lds(                                            \
        (const __attribute__((address_space(1))) void*)(g),                      \
        (__attribute__((address_space(3))) void*)(l), 16, 0, 0)

// ---------------- decompose: fp32 -> (hi, lo*2^12) fp16 ----------------
// h = RN16(v); r = v - h (exact); l = RN16(r * 4096)  [scale exact, then one RN]
// => |v - h - l*2^-12| <= 2^-12 |r| <= 2^-24 |v|
__global__ __launch_bounds__(256) void split_f32(const float* __restrict__ src,
                                                 _Float16* __restrict__ hi,
                                                 _Float16* __restrict__ lo,
                                                 size_t n_valid, size_t n_total) {
    size_t i4 = (size_t)(blockIdx.x * 256u + threadIdx.x) * 4;
    if (i4 >= n_total) return;
    float4 v;
    if (i4 < n_valid) v = *(const float4*)(src + i4);  // pad rows come after valid
    else              v = make_float4(0.f, 0.f, 0.f, 0.f);
    float vv[4] = {v.x, v.y, v.z, v.w};
#pragma unroll
    for (int j = 0; j < 4; ++j) {
        _Float16 h = (_Float16)vv[j];                  // RN
        float r = __fsub_rn(vv[j], (float)h);          // exact
        hi[i4 + j] = h;
        lo[i4 + j] = (_Float16)(r * 4096.0f);          // exact shift + RN; normal range
    }
}

// ---------------- split-fp16 MFMA GEMM (m97-style structure) ----------------
// C[M=2048, N=4096], K=8192. 128x128 block tile, BK=32, 4 waves of 64x64
// (4x4 frags of 16x16x32). Dual fp32 accumulators (scale 1 and scale 2^-12).
__global__ __launch_bounds__(256) void gemm_f16x2(const _Float16* __restrict__ A0,
                                                  const _Float16* __restrict__ A1,
                                                  const _Float16* __restrict__ B0,
                                                  const _Float16* __restrict__ B1,
                                                  float* __restrict__ C) {
    __shared__ _Float16 lds[4][128 * 32];  // A0,A1,B0,B1 tiles: 8 KB each = 32 KB

    const int tid  = threadIdx.x;
    const int wave = tid >> 6;
    const int lane = tid & 63;
    const int bm = blockIdx.y * 128;
    const int bn = blockIdx.x * 128;
    const int wm = (wave >> 1) * 64;
    const int wn = (wave & 1) * 64;

    // staging map: thread stages 16B at row tid/4, k-elem offset (tid%4)*8
    const int srow  = tid >> 2;       // 0..63
    const int skoff = (tid & 3) * 8;  // 0,8,16,24

    f32x4 acc0[4][4], acc1[4][4];
#pragma unroll
    for (int i = 0; i < 4; ++i)
#pragma unroll
        for (int j = 0; j < 4; ++j) {
            acc0[i][j] = (f32x4){0.f, 0.f, 0.f, 0.f};
            acc1[i][j] = (f32x4){0.f, 0.f, 0.f, 0.f};
        }

    const int quad = lane >> 4;  // 0..3
    const int l16  = lane & 15;

    for (int k0 = 0; k0 < NIN_K; k0 += 32) {
        __syncthreads();  // previous compute done before overwriting LDS
#pragma unroll
        for (int c = 0; c < 2; ++c) {  // two 64-row chunks per 128-row tile
            const size_t ga = (size_t)(bm + c * 64 + srow) * NIN_K + k0 + skoff;
            const size_t gb = (size_t)(bn + c * 64 + srow) * NIN_K + k0 + skoff;
            const int ldst = c * 2048 + wave * 512;  // halves; wave-uniform base
            GLL16(A0 + ga, &lds[0][ldst]);
            GLL16(A1 + ga, &lds[1][ldst]);
            GLL16(B0 + gb, &lds[2][ldst]);
            GLL16(B1 + gb, &lds[3][ldst]);
        }
        __syncthreads();  // drains vmcnt: staging complete

        half8 a0[4], a1[4], b0[4], b1[4];
#pragma unroll
        for (int i = 0; i < 4; ++i) {
            a0[i] = *(const half8*)&lds[0][(wm + i * 16 + l16) * 32 + quad * 8];
            a1[i] = *(const half8*)&lds[1][(wm + i * 16 + l16) * 32 + quad * 8];
            b0[i] = *(const half8*)&lds[2][(wn + i * 16 + l16) * 32 + quad * 8];
            b1[i] = *(const half8*)&lds[3][(wn + i * 16 + l16) * 32 + quad * 8];
        }
#pragma unroll
        for (int i = 0; i < 4; ++i)
#pragma unroll
            for (int j = 0; j < 4; ++j) {
                acc0[i][j] = __builtin_amdgcn_mfma_f32_16x16x32_f16(a0[i], b0[j], acc0[i][j], 0, 0, 0);
                acc1[i][j] = __builtin_amdgcn_mfma_f32_16x16x32_f16(a0[i], b1[j], acc1[i][j], 0, 0, 0);
                acc1[i][j] = __builtin_amdgcn_mfma_f32_16x16x32_f16(a1[i], b0[j], acc1[i][j], 0, 0, 0);
            }
    }

    // C/D layout (m89-verified): col = lane&15, row = (lane>>4)*4 + reg
    const float s = 1.0f / 4096.0f;  // 2^-12, exact
#pragma unroll
    for (int i = 0; i < 4; ++i)
#pragma unroll
        for (int j = 0; j < 4; ++j) {
            const int m = bm + wm + i * 16 + quad * 4;
            const int n = bn + wn + j * 16 + l16;
            float* cp = C + (size_t)m * NOUT_N + n;
#pragma unroll
            for (int r = 0; r < 4; ++r)
                cp[(size_t)r * NOUT_N] = __fmaf_rn(acc1[i][j][r], s, acc0[i][j][r]);
        }
}

// ---------------- fallback fp32 GEMM (round-1 proven) ----------------
#define BM 64
#define BN 64
#define BK 16
#define PAD 4
__global__ __launch_bounds__(256) void gemm_bt(const float* __restrict__ A,
                                               const float* __restrict__ B,
                                               float* __restrict__ C,
                                               int M, int N, int K) {
    __shared__ float As[BK][BM + PAD];
    __shared__ float Bs[BK][BN + PAD];
    const int bm = blockIdx.y * BM, bn = blockIdx.x * BN;
    const int tid = threadIdx.x;
    const int tx = tid & 15, ty = tid >> 4;
    const int lrow = tid >> 2, lk = (tid & 3) * 4;
    float acc[4][4];
#pragma unroll
    for (int i = 0; i < 4; ++i)
#pragma unroll
        for (int j = 0; j < 4; ++j) acc[i][j] = 0.0f;
    for (int k0 = 0; k0 < K; k0 += BK) {
        const int am = bm + lrow;
        float4 av = (am < M) ? *(const float4*)(A + (size_t)am * K + k0 + lk)
                             : make_float4(0.f, 0.f, 0.f, 0.f);
        As[lk + 0][lrow] = av.x; As[lk + 1][lrow] = av.y;
        As[lk + 2][lrow] = av.z; As[lk + 3][lrow] = av.w;
        float4 bv = *(const float4*)(B + (size_t)(bn + lrow) * K + k0 + lk);
        Bs[lk + 0][lrow] = bv.x; Bs[lk + 1][lrow] = bv.y;
        Bs[lk + 2][lrow] = bv.z; Bs[lk + 3][lrow] = bv.w;
        __syncthreads();
#pragma unroll
        for (int k = 0; k < BK; ++k) {
            float a[4], b[4];
#pragma unroll
            for (int i = 0; i < 4; ++i) a[i] = As[k][ty * 4 + i];
#pragma unroll
            for (int j = 0; j < 4; ++j) b[j] = Bs[k][tx * 4 + j];
#pragma unroll
            for (int i = 0; i < 4; ++i)
#pragma unroll
                for (int j = 0; j < 4; ++j) acc[i][j] += a[i] * b[j];
        }
        __syncthreads();
    }
#pragma unroll
    for (int i = 0; i < 4; ++i) {
        const int m = bm + ty * 4 + i;
        if (m < M) {
            float* cp = C + (size_t)m * N + bn + tx * 4;
#pragma unroll
            for (int j = 0; j < 4; ++j) cp[j] = acc[i][j];
        }
    }
}

// ---------------- sequential LIF scan (round-1 proven) ----------------
__global__ __launch_bounds__(64) void lif_scan(const float* __restrict__ inp,
                                               const float* __restrict__ v_th_p,
                                               const float* __restrict__ v_rest_p,
                                               const float* __restrict__ v_reset_p,
                                               const float* __restrict__ t_ref_p,
                                               const float* __restrict__ tau_p,
                                               float* __restrict__ out,
                                               int T, int N) {
    const int j = blockIdx.x * 64 + threadIdx.x;
    if (j >= N) return;
    const float vth = v_th_p[j], vrest = v_rest_p[j], vres = v_reset_p[j];
    const float tref = t_ref_p[j];
    const float c = __fmul_rn(0.001f, tau_p[j]);
    float v = vrest, refrac = 0.0f;
    out[j] = 0.0f;
#pragma unroll 8
    for (int t = 1; t < T; ++t) {
        const float in = inp[(size_t)t * N + j];
        const float d = __fmul_rn(c, __fsub_rn(v, vrest));
        v = __fsub_rn(v, d);
        v = (refrac == 0.0f) ? __fadd_rn(v, in) : v;
        refrac = (refrac > 0.0f) ? (refrac - 0.001f) : 0.0f;
        const bool s = (__fsub_rn(v, vth) >= 0.0f);
        out[(size_t)t * N + j] = s ? 1.0f : 0.0f;
        refrac = s ? tref : refrac;
        v = s ? vres : v;
    }
}

extern "C" void kernel_launch(void* const* d_in, const int* in_sizes, int n_in,
                              void* d_out, int out_size, void* d_ws, size_t ws_size,
                              hipStream_t stream) {
    const float* x       = (const float*)d_in[0];
    const float* w       = (const float*)d_in[1];
    const float* v_th    = (const float*)d_in[2];
    const float* v_rest  = (const float*)d_in[3];
    const float* v_reset = (const float*)d_in[4];
    const float* t_ref   = (const float*)d_in[5];
    const float* tau     = (const float*)d_in[6];
    float* out = (float*)d_out;

    // workspace layout
    const size_t LIF_B = (size_t)MPAD * NOUT_N * 4;        //  32 MiB
    const size_t XS_B  = (size_t)MPAD * NIN_K * 2;         //  32 MiB each
    const size_t WS_B  = (size_t)NOUT_N * NIN_K * 2;       //  64 MiB each
    const size_t NEED  = LIF_B + 2 * XS_B + 2 * WS_B;      // 224 MiB

    char* ws = (char*)d_ws;
    float* lif = (float*)ws;

    if (ws_size >= NEED) {
        _Float16* x0 = (_Float16*)(ws + LIF_B);
        _Float16* x1 = (_Float16*)(ws + LIF_B + XS_B);
        _Float16* w0 = (_Float16*)(ws + LIF_B + 2 * XS_B);
        _Float16* w1 = (_Float16*)(ws + LIF_B + 2 * XS_B + WS_B);

        const size_t nx = (size_t)MPAD * NIN_K;
        split_f32<<<nx / 4 / 256, 256, 0, stream>>>(x, x0, x1,
                                                    (size_t)T_STEPS * NIN_K, nx);
        const size_t nw = (size_t)NOUT_N * NIN_K;
        split_f32<<<nw / 4 / 256, 256, 0, stream>>>(w, w0, w1, nw, nw);

        dim3 g(NOUT_N / 128, MPAD / 128);
        gemm_f16x2<<<g, 256, 0, stream>>>(x0, x1, w0, w1, lif);
    } else {
        dim3 g(NOUT_N / BN, (T_STEPS + BM - 1) / BM);
        gemm_bt<<<g, 256, 0, stream>>>(x, w, lif, T_STEPS, NOUT_N, NIN_K);
    }

    lif_scan<<<NOUT_N / 64, 64, 0, stream>>>(lif, v_th, v_rest, v_reset, t_ref, tau,
                                             out, T_STEPS, NOUT_N);
}